// Round 3
// baseline (1005.737 us; speedup 1.0000x reference)
//
#include <hip/hip_runtime.h>
#include <hip/hip_bf16.h>

#define NN 10000
#define NE 640000
#define NF 128
#define NH 128
#define NT 128
#define KA 256   // NF + NH
#define LN_EPS 1e-5f

typedef __bf16 bf16x8 __attribute__((ext_vector_type(8)));
typedef float floatx4 __attribute__((ext_vector_type(4)));
typedef float nfloat4 __attribute__((ext_vector_type(4)));   // native clang vec for nontemporal builtins

__device__ inline unsigned short f2bf(float f) {
    unsigned int u = __float_as_uint(f);
    u += 0x7FFFu + ((u >> 16) & 1u);   // round-to-nearest-even
    return (unsigned short)(u >> 16);
}

__device__ inline bf16x8 load_frag(const unsigned short* p) {
    uint4 u = *(const uint4*)p;
    return __builtin_bit_cast(bf16x8, u);
}

// ---------------------------------------------------------------------------
// Prologue: convert weights f32 [K][N] -> bf16 [N][K] (transposed).
// ---------------------------------------------------------------------------
__global__ __launch_bounds__(256) void conv_weights(
    const float* __restrict__ W1a, const float* __restrict__ W1b,
    const float* __restrict__ W2a, const float* __restrict__ W2b,
    unsigned short* __restrict__ wt1a, unsigned short* __restrict__ wt1b,
    unsigned short* __restrict__ wt2a, unsigned short* __restrict__ wt2b)
{
    int tid = blockIdx.x * 256 + threadIdx.x;
    if (tid < 32768) {
        int n = tid >> 8, k = tid & 255;
        wt1a[tid] = f2bf(W1a[k * 128 + n]);
    } else if (tid < 49152) {
        int t = tid - 32768;
        int n = t >> 7, k = t & 127;
        wt1b[t] = f2bf(W1b[k * 128 + n]);
    } else if (tid < 81920) {
        int t = tid - 49152;
        int n = t >> 8, k = t & 255;
        wt2a[t] = f2bf(W2a[k * 128 + n]);
    } else if (tid < 98304) {
        int t = tid - 81920;
        int n = t >> 7, k = t & 127;
        wt2b[t] = f2bf(W2b[k * 128 + n]);
    }
}

// ---------------------------------------------------------------------------
// Counting sort by target row: hist -> scan -> scatter.
// ---------------------------------------------------------------------------
__global__ __launch_bounds__(256) void hist_kernel(
    const int* __restrict__ row, int* __restrict__ hist)
{
    int e = blockIdx.x * 256 + threadIdx.x;
    if (e < NE) atomicAdd(&hist[row[e]], 1);
}

__global__ __launch_bounds__(256) void scan_kernel(
    const int* __restrict__ hist, int* __restrict__ row_start,
    int* __restrict__ cursor)
{
    __shared__ int partials[256];
    const int t = threadIdx.x;
    const int base = t * 40;                  // 256*40 = 10240 >= NN
    int s = 0;
    for (int i = 0; i < 40; ++i) {
        int b = base + i;
        if (b < NN) s += hist[b];
    }
    partials[t] = s;
    __syncthreads();
    int pre = 0;
    for (int i = 0; i < t; ++i) pre += partials[i];
    int run = pre;
    for (int i = 0; i < 40; ++i) {
        int b = base + i;
        if (b < NN) {
            row_start[b] = run;
            cursor[b] = run;
            run += hist[b];
        }
    }
    if (t == 255) row_start[NN] = NE;
}

__global__ __launch_bounds__(256) void scatter_kernel(
    const int* __restrict__ row, int* __restrict__ cursor,
    int* __restrict__ perm)
{
    int e = blockIdx.x * 256 + threadIdx.x;
    if (e < NE) {
        int p = atomicAdd(&cursor[row[e]], 1);
        perm[p] = e;
    }
}

// ---------------------------------------------------------------------------
// Edge MLP on row-sorted edges + in-LDS segmented reduction.
// One wave = 16 edges, block = 4 waves = 64 sorted edges.
// b1b is NOT added here (moved to node kernel: mean(v+b) = mean(v)+b).
// ---------------------------------------------------------------------------
__global__ __launch_bounds__(256) void edge_mlp_kernel(
    const float* __restrict__ x,
    const int* __restrict__ erow, const int* __restrict__ ecol,
    const float* __restrict__ eattr,
    const int* __restrict__ perm,
    const unsigned short* __restrict__ wt1a, const float* __restrict__ b1a,
    const float* __restrict__ g1, const float* __restrict__ be1,
    const unsigned short* __restrict__ wt1b,
    float* __restrict__ sums)
{
    // accbuf [64][132] f32 (33792 B) unions with Atile [4][16][264] bf16
    // (33792 B): Atile is dead after the a1 fragment loads, which complete
    // before the post-Ttile __syncthreads; accbuf writes come after it.
    __shared__ float accbuf[64][132];
    __shared__ unsigned short Ttile[4][16][NH + 8];
    __shared__ int rows_s[64];
    unsigned short (*Atile)[16][KA + 8] = (unsigned short (*)[16][KA + 8])accbuf;

    const int wave = threadIdx.x >> 6;
    const int lane = threadIdx.x & 63;
    const int e0 = blockIdx.x * 64 + wave * 16;

    if (threadIdx.x < 64) {
        int e = perm[blockIdx.x * 64 + threadIdx.x];
        rows_s[threadIdx.x] = erow[e];
    }

    // ---- stage A = [x[col[e]] | edge_attr[e]] as bf16 into LDS ----
    {
        const int lrow = lane >> 2;      // 0..15 sorted-edge row
        const int lq   = lane & 3;
        const int e = perm[e0 + lrow];
        const int src = ecol[e];
        const nfloat4* xr = (const nfloat4*)(x + src * NF);
        const nfloat4* ar = (const nfloat4*)(eattr + (size_t)e * NH);
        unsigned short* Ar = &Atile[wave][lrow][0];
#pragma unroll
        for (int it = 0; it < 8; ++it) {
            int c4 = lq + it * 4;
            nfloat4 v = xr[c4];
            uint2 w;
            w.x = (unsigned)f2bf(v.x) | ((unsigned)f2bf(v.y) << 16);
            w.y = (unsigned)f2bf(v.z) | ((unsigned)f2bf(v.w) << 16);
            *(uint2*)&Ar[c4 * 4] = w;
            nfloat4 v2 = __builtin_nontemporal_load(ar + c4);
            uint2 w2;
            w2.x = (unsigned)f2bf(v2.x) | ((unsigned)f2bf(v2.y) << 16);
            w2.y = (unsigned)f2bf(v2.z) | ((unsigned)f2bf(v2.w) << 16);
            *(uint2*)&Ar[128 + c4 * 4] = w2;
        }
    }
    __syncthreads();

    const int lm  = lane & 15;
    const int lq4 = lane >> 4;

    // ---- GEMM1: [16 x 256] @ [256 x 128] ----
    bf16x8 a1[8];
#pragma unroll
    for (int ks = 0; ks < 8; ++ks)
        a1[ks] = load_frag(&Atile[wave][lm][ks * 32 + lq4 * 8]);

    floatx4 acc1[8];
#pragma unroll
    for (int ct = 0; ct < 8; ++ct) {
        floatx4 acc = {0.f, 0.f, 0.f, 0.f};
        const unsigned short* wr = wt1a + (ct * 16 + lm) * KA + lq4 * 8;
#pragma unroll
        for (int ks = 0; ks < 8; ++ks) {
            bf16x8 b = load_frag(wr + ks * 32);
            acc = __builtin_amdgcn_mfma_f32_16x16x32_bf16(a1[ks], b, acc, 0, 0, 0);
        }
        acc1[ct] = acc;
    }

    // ---- bias + ReLU + LayerNorm ----
    float sum_[4] = {0, 0, 0, 0}, sq_[4] = {0, 0, 0, 0};
#pragma unroll
    for (int ct = 0; ct < 8; ++ct) {
        const float bb = b1a[ct * 16 + lm];
#pragma unroll
        for (int i = 0; i < 4; ++i) {
            float v = acc1[ct][i] + bb;
            v = fmaxf(v, 0.f);
            acc1[ct][i] = v;
            sum_[i] += v;
            sq_[i]  += v * v;
        }
    }
#pragma unroll
    for (int m = 1; m < 16; m <<= 1) {
#pragma unroll
        for (int i = 0; i < 4; ++i) {
            sum_[i] += __shfl_xor(sum_[i], m, 64);
            sq_[i]  += __shfl_xor(sq_[i],  m, 64);
        }
    }
    float mu[4], rs[4];
#pragma unroll
    for (int i = 0; i < 4; ++i) {
        mu[i] = sum_[i] * (1.f / NH);
        float var = sq_[i] * (1.f / NH) - mu[i] * mu[i];
        rs[i] = rsqrtf(var + LN_EPS);
    }
#pragma unroll
    for (int ct = 0; ct < 8; ++ct) {
        const int c = ct * 16 + lm;
        const float gg = g1[c], bb = be1[c];
#pragma unroll
        for (int i = 0; i < 4; ++i) {
            float nv = (acc1[ct][i] - mu[i]) * rs[i] * gg + bb;
            Ttile[wave][lq4 * 4 + i][c] = f2bf(nv);
        }
    }
    __syncthreads();   // also fences Atile reads before accbuf overwrite

    // ---- GEMM2: [16 x 128] @ [128 x 128], write f32 to accbuf ----
    bf16x8 a2[4];
#pragma unroll
    for (int ks = 0; ks < 4; ++ks)
        a2[ks] = load_frag(&Ttile[wave][lm][ks * 32 + lq4 * 8]);

#pragma unroll
    for (int ct = 0; ct < 8; ++ct) {
        floatx4 acc = {0.f, 0.f, 0.f, 0.f};
        const unsigned short* wr = wt1b + (ct * 16 + lm) * NH + lq4 * 8;
#pragma unroll
        for (int ks = 0; ks < 4; ++ks) {
            bf16x8 b = load_frag(wr + ks * 32);
            acc = __builtin_amdgcn_mfma_f32_16x16x32_bf16(a2[ks], b, acc, 0, 0, 0);
        }
        const int c = ct * 16 + lm;
#pragma unroll
        for (int i = 0; i < 4; ++i)
            accbuf[wave * 16 + lq4 * 4 + i][c] = acc[i];
    }
    __syncthreads();

    // ---- segmented reduction over the block's 64 sorted edges ----
    {
        const int t = threadIdx.x;
        const int c = t & 127;
        const int jb = (t >> 7) * 32;          // two threads per column
        float a = 0.f;
        int cur = rows_s[jb];
#pragma unroll 4
        for (int j = jb; j < jb + 32; ++j) {
            a += accbuf[j][c];
            int nxt = (j + 1 < jb + 32) ? rows_s[j + 1] : -1;
            if (nxt != cur) {
                atomicAdd(&sums[cur * NH + c], a);
                a = 0.f;
                cur = nxt;
            }
        }
    }
}

// ---------------------------------------------------------------------------
// Node MLP: A = [x[n] | sums[n]/cnt + b1b (cnt>0)], direct store.
// ---------------------------------------------------------------------------
__global__ __launch_bounds__(256) void node_mlp_kernel(
    const float* __restrict__ x,
    const float* __restrict__ sums, const int* __restrict__ row_start,
    const float* __restrict__ b1b,
    const unsigned short* __restrict__ wt2a, const float* __restrict__ b2a,
    const float* __restrict__ g2, const float* __restrict__ be2,
    const unsigned short* __restrict__ wt2b, const float* __restrict__ b2b,
    float* __restrict__ out)
{
    __shared__ unsigned short Atile[4][16][KA + 8];
    __shared__ unsigned short Ttile[4][16][NH + 8];

    const int wave = threadIdx.x >> 6;
    const int lane = threadIdx.x & 63;
    const int n0 = blockIdx.x * 64 + wave * 16;

    {
        const int lrow = lane >> 2;
        const int lq   = lane & 3;
        int n = n0 + lrow;
        if (n >= NN) n = NN - 1;
        const int cntn = row_start[n + 1] - row_start[n];
        const float inv  = (cntn > 0) ? (1.f / (float)cntn) : 1.f;
        const float addb = (cntn > 0) ? 1.f : 0.f;
        const float4* xr = (const float4*)(x + n * NF);
        const float4* sr = (const float4*)(sums + n * NH);
        const float4* br = (const float4*)b1b;
        unsigned short* Ar = &Atile[wave][lrow][0];
#pragma unroll
        for (int it = 0; it < 8; ++it) {
            int c4 = lq + it * 4;
            float4 v = xr[c4];
            uint2 w;
            w.x = (unsigned)f2bf(v.x) | ((unsigned)f2bf(v.y) << 16);
            w.y = (unsigned)f2bf(v.z) | ((unsigned)f2bf(v.w) << 16);
            *(uint2*)&Ar[c4 * 4] = w;
            float4 v2 = sr[c4];
            float4 bv = br[c4];
            float a0 = v2.x * inv + addb * bv.x;
            float a1 = v2.y * inv + addb * bv.y;
            float a2 = v2.z * inv + addb * bv.z;
            float a3 = v2.w * inv + addb * bv.w;
            uint2 w2;
            w2.x = (unsigned)f2bf(a0) | ((unsigned)f2bf(a1) << 16);
            w2.y = (unsigned)f2bf(a2) | ((unsigned)f2bf(a3) << 16);
            *(uint2*)&Ar[128 + c4 * 4] = w2;
        }
    }
    __syncthreads();

    const int lm  = lane & 15;
    const int lq4 = lane >> 4;

    bf16x8 a1[8];
#pragma unroll
    for (int ks = 0; ks < 8; ++ks)
        a1[ks] = load_frag(&Atile[wave][lm][ks * 32 + lq4 * 8]);

    floatx4 acc1[8];
#pragma unroll
    for (int ct = 0; ct < 8; ++ct) {
        floatx4 acc = {0.f, 0.f, 0.f, 0.f};
        const unsigned short* wr = wt2a + (ct * 16 + lm) * KA + lq4 * 8;
#pragma unroll
        for (int ks = 0; ks < 8; ++ks) {
            bf16x8 b = load_frag(wr + ks * 32);
            acc = __builtin_amdgcn_mfma_f32_16x16x32_bf16(a1[ks], b, acc, 0, 0, 0);
        }
        acc1[ct] = acc;
    }

    float sum_[4] = {0, 0, 0, 0}, sq_[4] = {0, 0, 0, 0};
#pragma unroll
    for (int ct = 0; ct < 8; ++ct) {
        const float bb = b2a[ct * 16 + lm];
#pragma unroll
        for (int i = 0; i < 4; ++i) {
            float v = acc1[ct][i] + bb;
            v = fmaxf(v, 0.f);
            acc1[ct][i] = v;
            sum_[i] += v;
            sq_[i]  += v * v;
        }
    }
#pragma unroll
    for (int m = 1; m < 16; m <<= 1) {
#pragma unroll
        for (int i = 0; i < 4; ++i) {
            sum_[i] += __shfl_xor(sum_[i], m, 64);
            sq_[i]  += __shfl_xor(sq_[i],  m, 64);
        }
    }
    float mu[4], rs[4];
#pragma unroll
    for (int i = 0; i < 4; ++i) {
        mu[i] = sum_[i] * (1.f / NH);
        float var = sq_[i] * (1.f / NH) - mu[i] * mu[i];
        rs[i] = rsqrtf(var + LN_EPS);
    }
#pragma unroll
    for (int ct = 0; ct < 8; ++ct) {
        const int c = ct * 16 + lm;
        const float gg = g2[c], bb = be2[c];
#pragma unroll
        for (int i = 0; i < 4; ++i) {
            float nv = (acc1[ct][i] - mu[i]) * rs[i] * gg + bb;
            Ttile[wave][lq4 * 4 + i][c] = f2bf(nv);
        }
    }
    __syncthreads();

    bf16x8 a2[4];
#pragma unroll
    for (int ks = 0; ks < 4; ++ks)
        a2[ks] = load_frag(&Ttile[wave][lm][ks * 32 + lq4 * 8]);

#pragma unroll
    for (int ct = 0; ct < 8; ++ct) {
        floatx4 acc = {0.f, 0.f, 0.f, 0.f};
        const unsigned short* wr = wt2b + (ct * 16 + lm) * NH + lq4 * 8;
#pragma unroll
        for (int ks = 0; ks < 4; ++ks) {
            bf16x8 b = load_frag(wr + ks * 32);
            acc = __builtin_amdgcn_mfma_f32_16x16x32_bf16(a2[ks], b, acc, 0, 0, 0);
        }
        const int c = ct * 16 + lm;
        const float bb = b2b[c];
#pragma unroll
        for (int i = 0; i < 4; ++i) {
            int n = n0 + lq4 * 4 + i;
            if (n < NN) out[n * NT + c] = acc[i] + bb;
        }
    }
}

// ---------------------------------------------------------------------------
// Workspace layout (bytes):
//   [0,          5,120,000)  sums      f32 [10000][128]
//   [5,120,000,  5,160,000)  hist      int [10000]
//   [5,160,000,  5,200,000)  cursor    int [10000]
//   [5,200,000,  5,240,064)  row_start int [10001] (padded)
//   [5,240,064,  7,800,064)  perm      int [640000]
//   [7,800,064,  7,865,600)  wt1a      bf16 [128][256]
//   [7,865,600,  7,898,368)  wt1b      bf16 [128][128]
//   [7,898,368,  7,963,904)  wt2a      bf16 [128][256]
//   [7,963,904,  7,996,672)  wt2b      bf16 [128][128]
// ---------------------------------------------------------------------------
extern "C" void kernel_launch(void* const* d_in, const int* in_sizes, int n_in,
                              void* d_out, int out_size, void* d_ws, size_t ws_size,
                              hipStream_t stream) {
    const float* x     = (const float*)d_in[0];
    const int*   eidx  = (const int*)d_in[1];
    const float* eattr = (const float*)d_in[2];
    const float* W1a = (const float*)d_in[3];
    const float* b1a = (const float*)d_in[4];
    const float* g1  = (const float*)d_in[5];
    const float* be1 = (const float*)d_in[6];
    const float* W1b = (const float*)d_in[7];
    const float* b1b = (const float*)d_in[8];
    const float* W2a = (const float*)d_in[9];
    const float* b2a = (const float*)d_in[10];
    const float* g2  = (const float*)d_in[11];
    const float* be2 = (const float*)d_in[12];
    const float* W2b = (const float*)d_in[13];
    const float* b2b = (const float*)d_in[14];

    char* ws = (char*)d_ws;
    float* sums     = (float*)ws;
    int*   hist     = (int*)(ws + 5120000);
    int*   cursor   = (int*)(ws + 5160000);
    int*   row_start= (int*)(ws + 5200000);
    int*   perm     = (int*)(ws + 5240064);
    unsigned short* wt1a = (unsigned short*)(ws + 7800064);
    unsigned short* wt1b = (unsigned short*)(ws + 7865600);
    unsigned short* wt2a = (unsigned short*)(ws + 7898368);
    unsigned short* wt2b = (unsigned short*)(ws + 7963904);

    const int* erow = eidx;
    const int* ecol = eidx + NE;

    (void)hipMemsetAsync(ws, 0, 5160000, stream);   // zero sums + hist
    conv_weights<<<384, 256, 0, stream>>>(W1a, W1b, W2a, W2b, wt1a, wt1b, wt2a, wt2b);
    hist_kernel<<<(NE + 255) / 256, 256, 0, stream>>>(erow, hist);
    scan_kernel<<<1, 256, 0, stream>>>(hist, row_start, cursor);
    scatter_kernel<<<(NE + 255) / 256, 256, 0, stream>>>(erow, cursor, perm);
    edge_mlp_kernel<<<NE / 64, 256, 0, stream>>>(x, erow, ecol, eattr, perm,
                                                 wt1a, b1a, g1, be1, wt1b, sums);
    node_mlp_kernel<<<(NN + 63) / 64, 256, 0, stream>>>(x, sums, row_start, b1b,
                                                        wt2a, b2a, g2, be2, wt2b, b2b,
                                                        (float*)d_out);
}

// Round 4
// 717.073 us; speedup vs baseline: 1.4026x; 1.4026x over previous
//
#include <hip/hip_runtime.h>
#include <hip/hip_bf16.h>

#define NN 10000
#define NE 640000
#define NF 128
#define NH 128
#define NT 128
#define KA 256   // NF + NH
#define LN_EPS 1e-5f

typedef __bf16 bf16x8 __attribute__((ext_vector_type(8)));
typedef float floatx4 __attribute__((ext_vector_type(4)));
typedef float nfloat4 __attribute__((ext_vector_type(4)));

__device__ inline unsigned short f2bf(float f) {
    unsigned int u = __float_as_uint(f);
    u += 0x7FFFu + ((u >> 16) & 1u);   // round-to-nearest-even
    return (unsigned short)(u >> 16);
}

__device__ inline bf16x8 load_frag(const unsigned short* p) {
    uint4 u = *(const uint4*)p;
    return __builtin_bit_cast(bf16x8, u);
}

// ---------------------------------------------------------------------------
// Prologue: pack weights f32 [K][N] -> bf16 MFMA-fragment-major order.
// Fragment f=(ct*nks+ks): 64 lanes x 8 elems contiguous (1KB). Lane l holds
// B[k = ks*32 + (l>>4)*8 + j][n = ct*16 + (l&15)]  -> coalesced load_frag.
// ---------------------------------------------------------------------------
__global__ __launch_bounds__(256) void conv_weights(
    const float* __restrict__ W1a, const float* __restrict__ W1b,
    const float* __restrict__ W2a, const float* __restrict__ W2b,
    unsigned short* __restrict__ wp1a, unsigned short* __restrict__ wp1b,
    unsigned short* __restrict__ wp2a, unsigned short* __restrict__ wp2b)
{
    int tid = blockIdx.x * 256 + threadIdx.x;
    const float* src;
    unsigned short* dst;
    int t, nks;
    if (tid < 4096)        { src = W1a; dst = wp1a; t = tid;         nks = 8; }
    else if (tid < 6144)   { src = W1b; dst = wp1b; t = tid - 4096;  nks = 4; }
    else if (tid < 10240)  { src = W2a; dst = wp2a; t = tid - 6144;  nks = 8; }
    else if (tid < 12288)  { src = W2b; dst = wp2b; t = tid - 10240; nks = 4; }
    else return;

    const int f = t >> 6, l = t & 63;
    const int ct = f / nks, ks = f - ct * nks;
    const int n  = ct * 16 + (l & 15);
    const int k0 = ks * 32 + (l >> 4) * 8;
    unsigned short tmp[8];
#pragma unroll
    for (int j = 0; j < 8; ++j)
        tmp[j] = f2bf(src[(k0 + j) * 128 + n]);
    *(uint4*)&dst[t * 8] = *(const uint4*)tmp;
}

// ---------------------------------------------------------------------------
// Counting sort by target row: hist -> scan -> scatter.
// ---------------------------------------------------------------------------
__global__ __launch_bounds__(256) void hist_kernel(
    const int* __restrict__ row, int* __restrict__ hist)
{
    int e = blockIdx.x * 256 + threadIdx.x;
    if (e < NE) atomicAdd(&hist[row[e]], 1);
}

__global__ __launch_bounds__(256) void scan_kernel(
    const int* __restrict__ hist, int* __restrict__ row_start,
    int* __restrict__ cursor)
{
    __shared__ int partials[256];
    const int t = threadIdx.x;
    const int base = t * 40;                  // 256*40 = 10240 >= NN
    int s = 0;
    for (int i = 0; i < 40; ++i) {
        int b = base + i;
        if (b < NN) s += hist[b];
    }
    partials[t] = s;
    __syncthreads();
    int pre = 0;
    for (int i = 0; i < t; ++i) pre += partials[i];
    int run = pre;
    for (int i = 0; i < 40; ++i) {
        int b = base + i;
        if (b < NN) {
            row_start[b] = run;
            cursor[b] = run;
            run += hist[b];
        }
    }
    if (t == 255) row_start[NN] = NE;
}

__global__ __launch_bounds__(256) void scatter_kernel(
    const int* __restrict__ row, int* __restrict__ cursor,
    int* __restrict__ perm)
{
    int e = blockIdx.x * 256 + threadIdx.x;
    if (e < NE) {
        int p = atomicAdd(&cursor[row[e]], 1);
        perm[p] = e;
    }
}

// ---------------------------------------------------------------------------
// Edge MLP on row-sorted edges + in-LDS segmented reduction.
// One wave = 16 edges, block = 4 waves = 64 sorted edges.
// Weights come from fragment-packed wp1a/wp1b (coalesced 1KB loads).
// b1b moved to node kernel (mean(v+b) = mean(v)+b).
// ---------------------------------------------------------------------------
__global__ __launch_bounds__(256) void edge_mlp_kernel(
    const float* __restrict__ x,
    const int* __restrict__ erow, const int* __restrict__ ecol,
    const float* __restrict__ eattr,
    const int* __restrict__ perm,
    const unsigned short* __restrict__ wp1a, const float* __restrict__ b1a,
    const float* __restrict__ g1, const float* __restrict__ be1,
    const unsigned short* __restrict__ wp1b,
    float* __restrict__ sums)
{
    __shared__ float accbuf[64][132];
    __shared__ unsigned short Ttile[4][16][NH + 8];
    __shared__ int rows_s[64];
    unsigned short (*Atile)[16][KA + 8] = (unsigned short (*)[16][KA + 8])accbuf;

    const int wave = threadIdx.x >> 6;
    const int lane = threadIdx.x & 63;
    const int e0 = blockIdx.x * 64 + wave * 16;

    if (threadIdx.x < 64) {
        int e = perm[blockIdx.x * 64 + threadIdx.x];
        rows_s[threadIdx.x] = erow[e];
    }

    // ---- stage A = [x[col[e]] | edge_attr[e]] as bf16 into LDS ----
    {
        const int lrow = lane >> 2;
        const int lq   = lane & 3;
        const int e = perm[e0 + lrow];
        const int src = ecol[e];
        const nfloat4* xr = (const nfloat4*)(x + src * NF);
        const nfloat4* ar = (const nfloat4*)(eattr + (size_t)e * NH);
        unsigned short* Ar = &Atile[wave][lrow][0];
#pragma unroll
        for (int it = 0; it < 8; ++it) {
            int c4 = lq + it * 4;
            nfloat4 v = xr[c4];
            uint2 w;
            w.x = (unsigned)f2bf(v.x) | ((unsigned)f2bf(v.y) << 16);
            w.y = (unsigned)f2bf(v.z) | ((unsigned)f2bf(v.w) << 16);
            *(uint2*)&Ar[c4 * 4] = w;
            nfloat4 v2 = __builtin_nontemporal_load(ar + c4);
            uint2 w2;
            w2.x = (unsigned)f2bf(v2.x) | ((unsigned)f2bf(v2.y) << 16);
            w2.y = (unsigned)f2bf(v2.z) | ((unsigned)f2bf(v2.w) << 16);
            *(uint2*)&Ar[128 + c4 * 4] = w2;
        }
    }
    __syncthreads();

    const int lm  = lane & 15;
    const int lq4 = lane >> 4;

    // ---- GEMM1: [16 x 256] @ [256 x 128], packed-coalesced B ----
    bf16x8 a1[8];
#pragma unroll
    for (int ks = 0; ks < 8; ++ks)
        a1[ks] = load_frag(&Atile[wave][lm][ks * 32 + lq4 * 8]);

    floatx4 acc1[8];
#pragma unroll
    for (int ct = 0; ct < 8; ++ct) {
        floatx4 acc = {0.f, 0.f, 0.f, 0.f};
        const unsigned short* wr = wp1a + (ct * 8 * 64 + lane) * 8;
#pragma unroll
        for (int ks = 0; ks < 8; ++ks) {
            bf16x8 b = load_frag(wr + ks * 512);
            acc = __builtin_amdgcn_mfma_f32_16x16x32_bf16(a1[ks], b, acc, 0, 0, 0);
        }
        acc1[ct] = acc;
    }

    // ---- bias + ReLU + LayerNorm ----
    float sum_[4] = {0, 0, 0, 0}, sq_[4] = {0, 0, 0, 0};
#pragma unroll
    for (int ct = 0; ct < 8; ++ct) {
        const float bb = b1a[ct * 16 + lm];
#pragma unroll
        for (int i = 0; i < 4; ++i) {
            float v = acc1[ct][i] + bb;
            v = fmaxf(v, 0.f);
            acc1[ct][i] = v;
            sum_[i] += v;
            sq_[i]  += v * v;
        }
    }
#pragma unroll
    for (int m = 1; m < 16; m <<= 1) {
#pragma unroll
        for (int i = 0; i < 4; ++i) {
            sum_[i] += __shfl_xor(sum_[i], m, 64);
            sq_[i]  += __shfl_xor(sq_[i],  m, 64);
        }
    }
    float mu[4], rs[4];
#pragma unroll
    for (int i = 0; i < 4; ++i) {
        mu[i] = sum_[i] * (1.f / NH);
        float var = sq_[i] * (1.f / NH) - mu[i] * mu[i];
        rs[i] = rsqrtf(var + LN_EPS);
    }
#pragma unroll
    for (int ct = 0; ct < 8; ++ct) {
        const int c = ct * 16 + lm;
        const float gg = g1[c], bb = be1[c];
#pragma unroll
        for (int i = 0; i < 4; ++i) {
            float nv = (acc1[ct][i] - mu[i]) * rs[i] * gg + bb;
            Ttile[wave][lq4 * 4 + i][c] = f2bf(nv);
        }
    }
    __syncthreads();   // fences Atile reads before accbuf overwrite

    // ---- GEMM2: [16 x 128] @ [128 x 128], packed B, write f32 to accbuf ----
    bf16x8 a2[4];
#pragma unroll
    for (int ks = 0; ks < 4; ++ks)
        a2[ks] = load_frag(&Ttile[wave][lm][ks * 32 + lq4 * 8]);

#pragma unroll
    for (int ct = 0; ct < 8; ++ct) {
        floatx4 acc = {0.f, 0.f, 0.f, 0.f};
        const unsigned short* wr = wp1b + (ct * 4 * 64 + lane) * 8;
#pragma unroll
        for (int ks = 0; ks < 4; ++ks) {
            bf16x8 b = load_frag(wr + ks * 512);
            acc = __builtin_amdgcn_mfma_f32_16x16x32_bf16(a2[ks], b, acc, 0, 0, 0);
        }
        const int c = ct * 16 + lm;
#pragma unroll
        for (int i = 0; i < 4; ++i)
            accbuf[wave * 16 + lq4 * 4 + i][c] = acc[i];
    }
    __syncthreads();

    // ---- segmented reduction over the block's 64 sorted edges ----
    {
        const int t = threadIdx.x;
        const int c = t & 127;
        const int jb = (t >> 7) * 32;
        float a = 0.f;
        int cur = rows_s[jb];
#pragma unroll 4
        for (int j = jb; j < jb + 32; ++j) {
            a += accbuf[j][c];
            int nxt = (j + 1 < jb + 32) ? rows_s[j + 1] : -1;
            if (nxt != cur) {
                atomicAdd(&sums[cur * NH + c], a);
                a = 0.f;
                cur = nxt;
            }
        }
    }
}

// ---------------------------------------------------------------------------
// Node MLP: A = [x[n] | sums[n]/cnt + b1b (cnt>0)], packed weights.
// ---------------------------------------------------------------------------
__global__ __launch_bounds__(256) void node_mlp_kernel(
    const float* __restrict__ x,
    const float* __restrict__ sums, const int* __restrict__ row_start,
    const float* __restrict__ b1b,
    const unsigned short* __restrict__ wp2a, const float* __restrict__ b2a,
    const float* __restrict__ g2, const float* __restrict__ be2,
    const unsigned short* __restrict__ wp2b, const float* __restrict__ b2b,
    float* __restrict__ out)
{
    __shared__ unsigned short Atile[4][16][KA + 8];
    __shared__ unsigned short Ttile[4][16][NH + 8];

    const int wave = threadIdx.x >> 6;
    const int lane = threadIdx.x & 63;
    const int n0 = blockIdx.x * 64 + wave * 16;

    {
        const int lrow = lane >> 2;
        const int lq   = lane & 3;
        int n = n0 + lrow;
        if (n >= NN) n = NN - 1;
        const int cntn = row_start[n + 1] - row_start[n];
        const float inv  = (cntn > 0) ? (1.f / (float)cntn) : 1.f;
        const float addb = (cntn > 0) ? 1.f : 0.f;
        const float4* xr = (const float4*)(x + n * NF);
        const float4* sr = (const float4*)(sums + n * NH);
        const float4* br = (const float4*)b1b;
        unsigned short* Ar = &Atile[wave][lrow][0];
#pragma unroll
        for (int it = 0; it < 8; ++it) {
            int c4 = lq + it * 4;
            float4 v = xr[c4];
            uint2 w;
            w.x = (unsigned)f2bf(v.x) | ((unsigned)f2bf(v.y) << 16);
            w.y = (unsigned)f2bf(v.z) | ((unsigned)f2bf(v.w) << 16);
            *(uint2*)&Ar[c4 * 4] = w;
            float4 v2 = sr[c4];
            float4 bv = br[c4];
            float a0 = v2.x * inv + addb * bv.x;
            float a1 = v2.y * inv + addb * bv.y;
            float a2 = v2.z * inv + addb * bv.z;
            float a3 = v2.w * inv + addb * bv.w;
            uint2 w2;
            w2.x = (unsigned)f2bf(a0) | ((unsigned)f2bf(a1) << 16);
            w2.y = (unsigned)f2bf(a2) | ((unsigned)f2bf(a3) << 16);
            *(uint2*)&Ar[128 + c4 * 4] = w2;
        }
    }
    __syncthreads();

    const int lm  = lane & 15;
    const int lq4 = lane >> 4;

    bf16x8 a1[8];
#pragma unroll
    for (int ks = 0; ks < 8; ++ks)
        a1[ks] = load_frag(&Atile[wave][lm][ks * 32 + lq4 * 8]);

    floatx4 acc1[8];
#pragma unroll
    for (int ct = 0; ct < 8; ++ct) {
        floatx4 acc = {0.f, 0.f, 0.f, 0.f};
        const unsigned short* wr = wp2a + (ct * 8 * 64 + lane) * 8;
#pragma unroll
        for (int ks = 0; ks < 8; ++ks) {
            bf16x8 b = load_frag(wr + ks * 512);
            acc = __builtin_amdgcn_mfma_f32_16x16x32_bf16(a1[ks], b, acc, 0, 0, 0);
        }
        acc1[ct] = acc;
    }

    float sum_[4] = {0, 0, 0, 0}, sq_[4] = {0, 0, 0, 0};
#pragma unroll
    for (int ct = 0; ct < 8; ++ct) {
        const float bb = b2a[ct * 16 + lm];
#pragma unroll
        for (int i = 0; i < 4; ++i) {
            float v = acc1[ct][i] + bb;
            v = fmaxf(v, 0.f);
            acc1[ct][i] = v;
            sum_[i] += v;
            sq_[i]  += v * v;
        }
    }
#pragma unroll
    for (int m = 1; m < 16; m <<= 1) {
#pragma unroll
        for (int i = 0; i < 4; ++i) {
            sum_[i] += __shfl_xor(sum_[i], m, 64);
            sq_[i]  += __shfl_xor(sq_[i],  m, 64);
        }
    }
    float mu[4], rs[4];
#pragma unroll
    for (int i = 0; i < 4; ++i) {
        mu[i] = sum_[i] * (1.f / NH);
        float var = sq_[i] * (1.f / NH) - mu[i] * mu[i];
        rs[i] = rsqrtf(var + LN_EPS);
    }
#pragma unroll
    for (int ct = 0; ct < 8; ++ct) {
        const int c = ct * 16 + lm;
        const float gg = g2[c], bb = be2[c];
#pragma unroll
        for (int i = 0; i < 4; ++i) {
            float nv = (acc1[ct][i] - mu[i]) * rs[i] * gg + bb;
            Ttile[wave][lq4 * 4 + i][c] = f2bf(nv);
        }
    }
    __syncthreads();

    bf16x8 a2[4];
#pragma unroll
    for (int ks = 0; ks < 4; ++ks)
        a2[ks] = load_frag(&Ttile[wave][lm][ks * 32 + lq4 * 8]);

#pragma unroll
    for (int ct = 0; ct < 8; ++ct) {
        floatx4 acc = {0.f, 0.f, 0.f, 0.f};
        const unsigned short* wr = wp2b + (ct * 4 * 64 + lane) * 8;
#pragma unroll
        for (int ks = 0; ks < 4; ++ks) {
            bf16x8 b = load_frag(wr + ks * 512);
            acc = __builtin_amdgcn_mfma_f32_16x16x32_bf16(a2[ks], b, acc, 0, 0, 0);
        }
        const int c = ct * 16 + lm;
        const float bb = b2b[c];
#pragma unroll
        for (int i = 0; i < 4; ++i) {
            int n = n0 + lq4 * 4 + i;
            if (n < NN) out[n * NT + c] = acc[i] + bb;
        }
    }
}

// ---------------------------------------------------------------------------
// Workspace layout (bytes):
//   [0,          5,120,000)  sums      f32 [10000][128]
//   [5,120,000,  5,160,000)  hist      int [10000]
//   [5,160,000,  5,200,000)  cursor    int [10000]
//   [5,200,000,  5,240,064)  row_start int [10001] (padded)
//   [5,240,064,  7,800,064)  perm      int [640000]
//   [7,800,064,  7,865,600)  wp1a      bf16 frag-packed [64 frags][64 lanes][8]
//   [7,865,600,  7,898,368)  wp1b      bf16 frag-packed [32][64][8]
//   [7,898,368,  7,963,904)  wp2a      bf16 frag-packed [64][64][8]
//   [7,963,904,  7,996,672)  wp2b      bf16 frag-packed [32][64][8]
// ---------------------------------------------------------------------------
extern "C" void kernel_launch(void* const* d_in, const int* in_sizes, int n_in,
                              void* d_out, int out_size, void* d_ws, size_t ws_size,
                              hipStream_t stream) {
    const float* x     = (const float*)d_in[0];
    const int*   eidx  = (const int*)d_in[1];
    const float* eattr = (const float*)d_in[2];
    const float* W1a = (const float*)d_in[3];
    const float* b1a = (const float*)d_in[4];
    const float* g1  = (const float*)d_in[5];
    const float* be1 = (const float*)d_in[6];
    const float* W1b = (const float*)d_in[7];
    const float* b1b = (const float*)d_in[8];
    const float* W2a = (const float*)d_in[9];
    const float* b2a = (const float*)d_in[10];
    const float* g2  = (const float*)d_in[11];
    const float* be2 = (const float*)d_in[12];
    const float* W2b = (const float*)d_in[13];
    const float* b2b = (const float*)d_in[14];

    char* ws = (char*)d_ws;
    float* sums     = (float*)ws;
    int*   hist     = (int*)(ws + 5120000);
    int*   cursor   = (int*)(ws + 5160000);
    int*   row_start= (int*)(ws + 5200000);
    int*   perm     = (int*)(ws + 5240064);
    unsigned short* wp1a = (unsigned short*)(ws + 7800064);
    unsigned short* wp1b = (unsigned short*)(ws + 7865600);
    unsigned short* wp2a = (unsigned short*)(ws + 7898368);
    unsigned short* wp2b = (unsigned short*)(ws + 7963904);

    const int* erow = eidx;
    const int* ecol = eidx + NE;

    (void)hipMemsetAsync(ws, 0, 5160000, stream);   // zero sums + hist
    conv_weights<<<48, 256, 0, stream>>>(W1a, W1b, W2a, W2b, wp1a, wp1b, wp2a, wp2b);
    hist_kernel<<<(NE + 255) / 256, 256, 0, stream>>>(erow, hist);
    scan_kernel<<<1, 256, 0, stream>>>(hist, row_start, cursor);
    scatter_kernel<<<(NE + 255) / 256, 256, 0, stream>>>(erow, cursor, perm);
    edge_mlp_kernel<<<NE / 64, 256, 0, stream>>>(x, erow, ecol, eattr, perm,
                                                 wp1a, b1a, g1, be1, wp1b, sums);
    node_mlp_kernel<<<(NN + 63) / 64, 256, 0, stream>>>(x, sums, row_start, b1b,
                                                        wp2a, b2a, g2, be2, wp2b, b2b,
                                                        (float*)d_out);
}